// Round 4
// baseline (754.406 us; speedup 1.0000x reference)
//
#include <hip/hip_runtime.h>
#include <hip/hip_bf16.h>
#include <math.h>

#define S_LEN 2048
#define NHEADS 71
#define HDIM 64
#define HSZ (NHEADS * HDIM)        // 4544
#define QKVN ((NHEADS + 2) * HDIM) // 4672
#define QKVP 4736                  // QKVN padded to 128
#define DNP  4608                  // HSZ padded to 128

typedef unsigned short u16;
typedef __attribute__((ext_vector_type(8))) short short8;
typedef __attribute__((ext_vector_type(4))) short bfx4;   // renamed: short4 collides with HIP
typedef __attribute__((ext_vector_type(4))) float floatx4;

__device__ __forceinline__ float bf2f(u16 v) {
    unsigned u = ((unsigned)v) << 16;
    return __builtin_bit_cast(float, u);
}
__device__ __forceinline__ u16 f2bf(float f) {
    unsigned u = __builtin_bit_cast(unsigned, f);
    u += 0x7fff + ((u >> 16) & 1);   // RNE
    return (u16)(u >> 16);
}

// async global->LDS, 16B per lane (wave-uniform LDS base + lane*16)
__device__ __forceinline__ void async16(const u16* g, u16* l) {
    __builtin_amdgcn_global_load_lds(
        (const __attribute__((address_space(1))) void*)g,
        (__attribute__((address_space(3))) void*)l,
        16, 0, 0);
}

// ===========================================================================
// fp32 -> bf16 elementwise (n divisible by 8)
// ===========================================================================
__global__ __launch_bounds__(256) void convert_bf16(const float* __restrict__ src,
                                                    u16* __restrict__ dst, int n)
{
    int i = (blockIdx.x * 256 + threadIdx.x) * 8;
    if (i >= n) return;
    floatx4 a = *(const floatx4*)(src + i);
    floatx4 b = *(const floatx4*)(src + i + 4);
    u16 o[8];
#pragma unroll
    for (int j = 0; j < 4; ++j) { o[j] = f2bf(a[j]); o[4 + j] = f2bf(b[j]); }
    *(short8*)(dst + i) = *(short8*)&o[0];
}

// fp32 src[K][Ns]  ->  bf16 dst[Np][K] (transposed, rows n>=Ns zero-padded)
__global__ __launch_bounds__(256) void conv_transpose(const float* __restrict__ src,
                                                      u16* __restrict__ dst,
                                                      int K, int Ns)
{
    __shared__ float t[32][33];
    const int k0 = blockIdx.x * 32, n0 = blockIdx.y * 32;
    const int tx = threadIdx.x & 31, ty = threadIdx.x >> 5;
#pragma unroll
    for (int i = 0; i < 4; ++i) {
        int r = ty + i * 8;
        int n = n0 + tx;
        t[r][tx] = (n < Ns) ? src[(size_t)(k0 + r) * Ns + n] : 0.f;
    }
    __syncthreads();
#pragma unroll
    for (int i = 0; i < 4; ++i) {
        int rr = ty + i * 8;
        dst[(size_t)(n0 + rr) * K + k0 + tx] = f2bf(t[tx][rr]);
    }
}

// ===========================================================================
// gemm128 v3: m97 structure + 2-phase LDS dbuf + XCD col-major dispatch remap.
// R3 counters: FETCH_SIZE 320MB vs 63MB ideal -> B re-streamed from HBM
// (x-fastest dispatch puts same-B-panel blocks on different XCDs/L2s).
// Remap: XCD g owns a contiguous COL-MAJOR chunk of the tile grid, so a
// 581KB B-panel stays hot in its 4MB L2 for 16 consecutive blocks; B is
// HBM-fetched once, A cycles via L3. Load latency ~900cy (HBM) -> ~200cy
// (L2 hit), which the dbuf's ~160cy of MFMA can mostly cover.
// Bijective when nwg%8==0 (592 and 576 both are); identity fallback else.
// ===========================================================================
template <bool STORE_F32>
__global__ __launch_bounds__(256) void gemm128(const u16* __restrict__ A,   // [M][K]
                                               const u16* __restrict__ Bt,  // [Np][K]
                                               void* __restrict__ Cv,
                                               int M, int K, int Np, int Nreal)
{
    __shared__ u16 As[2 * 128 * 64];
    __shared__ u16 Bs[2 * 128 * 64];

    const int tid  = threadIdx.x;
    const int w    = tid >> 6, lane = tid & 63;
    const int l15  = lane & 15, quad = lane >> 4;

    // ---- XCD-aware remap: dispatch id L -> col-major chunk per XCD ----
    int bx = blockIdx.x, by = blockIdx.y;
    {
        const int nbx = gridDim.x, nby = gridDim.y;
        const int nwg = nbx * nby;
        if ((nwg & 7) == 0) {
            const int L   = by * nbx + bx;      // dispatch-linear (x fastest)
            const int g   = L & 7;              // empirical XCD round-robin
            const int s   = L >> 3;             // slot within XCD
            const int CM  = g * (nwg >> 3) + s; // col-major block index
            bx = CM / nby;
            by = CM % nby;
        }
    }
    const int bm = by * 128, bn = bx * 128;
    const int wm = (w >> 1) * 64, wn = (w & 1) * 64;

    floatx4 acc[4][4] = {};

    const int srow = w * 32 + (lane >> 3);
    const int scol = (lane & 7) * 8;
    const u16* Ab = A  + (size_t)(bm + srow) * K + scol;
    const u16* Bb = Bt + (size_t)(bn + srow) * K + scol;
    const int woff = (w * 32) * 64;

    const int nkt = K >> 6;   // K/64

    // ---- prologue: stage tile 0 into buffer 0 ----
#pragma unroll
    for (int i = 0; i < 4; ++i)
        async16(Ab + (size_t)(i * 8) * K, As + woff + i * 8 * 64);
#pragma unroll
    for (int i = 0; i < 4; ++i)
        async16(Bb + (size_t)(i * 8) * K, Bs + woff + i * 8 * 64);
    __syncthreads();   // compiler drains vmcnt(0) before s_barrier -> tile 0 ready

    for (int t = 0; t < nkt; ++t) {
        const int cur = t & 1;
        const u16* Asc = As + cur * (128 * 64);
        const u16* Bsc = Bs + cur * (128 * 64);

        // ---- issue next tile's async loads into the other buffer ----
        if (t + 1 < nkt) {
            const int kb = (t + 1) << 6;
            u16* Asn = As + (cur ^ 1) * (128 * 64) + woff;
            u16* Bsn = Bs + (cur ^ 1) * (128 * 64) + woff;
#pragma unroll
            for (int i = 0; i < 4; ++i)
                async16(Ab + (size_t)(i * 8) * K + kb, Asn + i * 8 * 64);
#pragma unroll
            for (int i = 0; i < 4; ++i)
                async16(Bb + (size_t)(i * 8) * K + kb, Bsn + i * 8 * 64);
        }

        // ---- compute current tile (loads for it completed last iteration) ----
#pragma unroll
        for (int kk = 0; kk < 2; ++kk) {
            short8 af[4], bfr[4];
#pragma unroll
            for (int tt = 0; tt < 4; ++tt) {
                af[tt]  = *(const short8*)&Asc[(wm + tt * 16 + l15) * 64 + kk * 32 + quad * 8];
                bfr[tt] = *(const short8*)&Bsc[(wn + tt * 16 + l15) * 64 + kk * 32 + quad * 8];
            }
#pragma unroll
            for (int mi = 0; mi < 4; ++mi)
#pragma unroll
                for (int ni = 0; ni < 4; ++ni)
                    acc[mi][ni] = __builtin_amdgcn_mfma_f32_16x16x32_bf16(
                        af[mi], bfr[ni], acc[mi][ni], 0, 0, 0);
        }

        // barrier: waits for next tile's stage (vmcnt drain) + all ds_reads done,
        // so the buffer swap is race-free.
        __syncthreads();
    }

    if (STORE_F32) {
        float* C = (float*)Cv;
#pragma unroll
        for (int mi = 0; mi < 4; ++mi)
#pragma unroll
            for (int ni = 0; ni < 4; ++ni) {
                int col  = bn + wn + ni * 16 + l15;
                int row0 = bm + wm + mi * 16 + quad * 4;
                if (col < Nreal) {
#pragma unroll
                    for (int r = 0; r < 4; ++r)
                        C[(size_t)(row0 + r) * Nreal + col] = acc[mi][ni][r];
                }
            }
    } else {
        u16* C = (u16*)Cv;
#pragma unroll
        for (int mi = 0; mi < 4; ++mi)
#pragma unroll
            for (int ni = 0; ni < 4; ++ni) {
                int col  = bn + wn + ni * 16 + l15;
                int row0 = bm + wm + mi * 16 + quad * 4;
#pragma unroll
                for (int r = 0; r < 4; ++r)
                    C[(size_t)(row0 + r) * Np + col] = f2bf(acc[mi][ni][r]);
            }
    }
}

// ===========================================================================
// RoPE for K + V transposed to [HDIM][S_LEN]
// ===========================================================================
__global__ void rope_kv(const u16* __restrict__ qkv, int QP,
                        u16* __restrict__ Kr,   // [S][64]
                        u16* __restrict__ VT)   // [64][S]
{
    int idx = blockIdx.x * 256 + threadIdx.x;  // over S_LEN * 128
    int s = idx >> 7;
    int c = idx & 127;
    if (c < HDIM) {
        int d = c;
        float x  = bf2f(qkv[(size_t)s * QP + HSZ + d]);
        int dp   = (d < 32) ? d + 32 : d - 32;
        float rot = (d < 32) ? -bf2f(qkv[(size_t)s * QP + HSZ + dp])
                             :  bf2f(qkv[(size_t)s * QP + HSZ + dp]);
        float invf = expf(-(float)(d & 31) * 0.28782313662425572f);
        float ang  = (float)s * invf;
        float o = x * cosf(ang) + rot * sinf(ang);
        Kr[(size_t)s * HDIM + d] = f2bf(o);
    } else {
        int d = c - HDIM;
        VT[(size_t)d * S_LEN + s] = qkv[(size_t)s * QP + (NHEADS + 1) * HDIM + d];
    }
}

// ===========================================================================
// Fused causal attention v3: transposed-score formulation.
//  S^T = K·Q^T  (C rows = t, cols = q)  -> per-lane softmax state (q = lane&15)
//  O^T = V^T·P^T via 16x16x32, FULL-K: two adjacent 16-t subtiles packed into
//  k-slots 0-3 / 4-7 of one MFMA (halves PV MFMA count vs half-K trick).
// Block = (head, q-tile of 64 rows) , 4 waves x 16 q rows. 128-t chunks.
// ===========================================================================
__global__ __launch_bounds__(256) void attn2(const u16* __restrict__ qkv, int QP,
                                             const u16* __restrict__ Kr,   // [S][64]
                                             const u16* __restrict__ VT,   // [64][S]
                                             u16* __restrict__ O)          // [S][HSZ]
{
    __shared__ u16 Kt[128][72];    // [t][d]   row stride 144 B
    __shared__ u16 Vt[64][136];    // [d][t]   row stride 272 B

    const int tid  = threadIdx.x;
    const int h    = blockIdx.x;
    const int qt   = 31 - blockIdx.y;    // longest blocks dispatch first
    const int qs   = qt * 64;
    const int w    = tid >> 6;
    const int lane = tid & 63;
    const int l15  = lane & 15;
    const int quad = lane >> 4;

    // ---- Q fragments (B-operand layout: n=q=l15, k=d=quad*8+j), RoPE+scale ----
    const int q_row = qs + w * 16 + l15;
    const u16* qp = qkv + (size_t)q_row * QP + h * HDIM;
    short8 r0 = *(const short8*)(qp + quad * 8);
    short8 r1 = *(const short8*)(qp + 32 + quad * 8);
    short8 qf0, qf1;
#pragma unroll
    for (int j = 0; j < 8; ++j) {
        int d0 = quad * 8 + j;
        float invf = expf(-(float)d0 * 0.28782313662425572f);
        float ang  = (float)q_row * invf;
        float cs = cosf(ang), sn = sinf(ang);
        float x0 = bf2f((u16)r0[j]), x1 = bf2f((u16)r1[j]);
        qf0[j] = (short)f2bf((x0 * cs - x1 * sn) * 0.125f);
        qf1[j] = (short)f2bf((x1 * cs + x0 * sn) * 0.125f);
    }

    floatx4 ot0 = {0.f,0.f,0.f,0.f}, ot1 = {0.f,0.f,0.f,0.f};
    floatx4 ot2 = {0.f,0.f,0.f,0.f}, ot3 = {0.f,0.f,0.f,0.f};
    float m_p = -1e30f, l_p = 0.f;
    const int qmin_w  = qs + w * 16;
    const int nchunks = (qt + 2) >> 1;

    const int krow = tid >> 1, kcol = (tid & 1) * 32;
    const int vrow = tid >> 2, vcol = (tid & 3) * 32;

    for (int c = 0; c < nchunks; ++c) {
        const int cbase = c * 128;

        // ---- prefetch chunk to regs (overlaps prior compute), then stage ----
        const u16* kp = Kr + (size_t)(cbase + krow) * HDIM + kcol;
        short8 k0 = *(const short8*)(kp);
        short8 k1 = *(const short8*)(kp + 8);
        short8 k2 = *(const short8*)(kp + 16);
        short8 k3 = *(const short8*)(kp + 24);
        const u16* vp = VT + (size_t)vrow * S_LEN + cbase + vcol;
        short8 v0 = *(const short8*)(vp);
        short8 v1 = *(const short8*)(vp + 8);
        short8 v2 = *(const short8*)(vp + 16);
        short8 v3 = *(const short8*)(vp + 24);
        __syncthreads();
        *(short8*)&Kt[krow][kcol]      = k0;
        *(short8*)&Kt[krow][kcol + 8]  = k1;
        *(short8*)&Kt[krow][kcol + 16] = k2;
        *(short8*)&Kt[krow][kcol + 24] = k3;
        *(short8*)&Vt[vrow][vcol]      = v0;
        *(short8*)&Vt[vrow][vcol + 8]  = v1;
        *(short8*)&Vt[vrow][vcol + 16] = v2;
        *(short8*)&Vt[vrow][vcol + 24] = v3;
        __syncthreads();

        // ---- active 16-t subtiles for this wave (causal early-out) ----
        const int nsub = min(8, ((qmin_w - cbase) >> 4) + 1);

        // ---- scores S^T: rows t = cbase + s*16 + quad*4 + r, col q = l15 ----
        floatx4 sc[8];
        float tmax = -3e38f;
#pragma unroll
        for (int s = 0; s < 8; ++s) {
            if (s < nsub) {
                short8 ka = *(const short8*)&Kt[s * 16 + l15][quad * 8];
                short8 kb = *(const short8*)&Kt[s * 16 + l15][32 + quad * 8];
                floatx4 a = {0.f,0.f,0.f,0.f};
                __builtin_amdgcn_s_setprio(1);
                a = __builtin_amdgcn_mfma_f32_16x16x32_bf16(ka, qf0, a, 0, 0, 0);
                a = __builtin_amdgcn_mfma_f32_16x16x32_bf16(kb, qf1, a, 0, 0, 0);
                __builtin_amdgcn_s_setprio(0);
                if (cbase + s * 16 + 15 > qmin_w) {   // diagonal subtile: mask t>q
                    int tb = cbase + s * 16 + quad * 4;
#pragma unroll
                    for (int r = 0; r < 4; ++r)
                        if (tb + r > q_row) a[r] = -1e30f;
                }
                sc[s] = a;
                tmax = fmaxf(tmax, fmaxf(fmaxf(a[0], a[1]), fmaxf(a[2], a[3])));
            }
        }
        // reduce over t across quads (lanes sharing l15=q): 2 shuffles
        tmax = fmaxf(tmax, __shfl_xor(tmax, 16, 64));
        tmax = fmaxf(tmax, __shfl_xor(tmax, 32, 64));

        float mnew = fmaxf(m_p, tmax);
        float al   = __expf(m_p - mnew);
        m_p = mnew;
        ot0 *= al; ot1 *= al; ot2 *= al; ot3 *= al;

        float lsum = 0.f;
        // ---- PV: pair subtiles (s, s+1) into one full-K=32 MFMA group ----
#pragma unroll
        for (int s = 0; s < 8; s += 2) {
            if (s < nsub) {
                const bool two = (s + 1 < nsub);   // wave-uniform
                float p0 = __expf(sc[s][0] - mnew);
                float p1 = __expf(sc[s][1] - mnew);
                float p2 = __expf(sc[s][2] - mnew);
                float p3 = __expf(sc[s][3] - mnew);
                float p4 = 0.f, p5 = 0.f, p6 = 0.f, p7 = 0.f;
                if (two) {
                    p4 = __expf(sc[s + 1][0] - mnew);
                    p5 = __expf(sc[s + 1][1] - mnew);
                    p6 = __expf(sc[s + 1][2] - mnew);
                    p7 = __expf(sc[s + 1][3] - mnew);
                }
                lsum += ((p0 + p1) + (p2 + p3)) + ((p4 + p5) + (p6 + p7));
                short8 pb = { (short)f2bf(p0), (short)f2bf(p1),
                              (short)f2bf(p2), (short)f2bf(p3),
                              (short)f2bf(p4), (short)f2bf(p5),
                              (short)f2bf(p6), (short)f2bf(p7) };
                const int vc0 = s * 16 + quad * 4;
                const int vc1 = vc0 + 16;
                bfx4 z = {0, 0, 0, 0};
                bfx4 lo0 = *(const bfx4*)&Vt[l15][vc0];
                bfx4 lo1 = *(const bfx4*)&Vt[16 + l15][vc0];
                bfx4 lo2 = *(const bfx4*)&Vt[32 + l15][vc0];
                bfx4 lo3 = *(const bfx4*)&Vt[48 + l15][vc0];
                bfx4 hi0 = z, hi1 = z, hi2 = z, hi3 = z;
                if (two) {
                    hi0 = *(const bfx4*)&Vt[l15][vc1];
                    hi1 = *(const bfx4*)&Vt[16 + l15][vc1];
                    hi2 = *(const bfx4*)&Vt[32 + l15][vc1];
                    hi3 = *(const bfx4*)&Vt[48 + l15][vc1];
                }
                short8 a0 = { lo0[0], lo0[1], lo0[2], lo0[3], hi0[0], hi0[1], hi0[2], hi0[3] };
                short8 a1 = { lo1[0], lo1[1], lo1[2], lo1[3], hi1[0], hi1[1], hi1[2], hi1[3] };
                short8 a2 = { lo2[0], lo2[1], lo2[2], lo2[3], hi2[0], hi2[1], hi2[2], hi2[3] };
                short8 a3 = { lo3[0], lo3[1], lo3[2], lo3[3], hi3[0], hi3[1], hi3[2], hi3[3] };
                __builtin_amdgcn_s_setprio(1);
                ot0 = __builtin_amdgcn_mfma_f32_16x16x32_bf16(a0, pb, ot0, 0, 0, 0);
                ot1 = __builtin_amdgcn_mfma_f32_16x16x32_bf16(a1, pb, ot1, 0, 0, 0);
                ot2 = __builtin_amdgcn_mfma_f32_16x16x32_bf16(a2, pb, ot2, 0, 0, 0);
                ot3 = __builtin_amdgcn_mfma_f32_16x16x32_bf16(a3, pb, ot3, 0, 0, 0);
                __builtin_amdgcn_s_setprio(0);
            }
        }
        lsum += __shfl_xor(lsum, 16, 64);
        lsum += __shfl_xor(lsum, 32, 64);
        l_p = l_p * al + lsum;
    }

    // ---- epilogue: O^T rows d = dt*16 + quad*4 + r, col q = l15 ----
    float inv = 1.0f / l_p;
    u16* op = O + (size_t)q_row * HSZ + h * HDIM + quad * 4;
    bfx4 s0 = { (short)f2bf(ot0[0]*inv), (short)f2bf(ot0[1]*inv),
                (short)f2bf(ot0[2]*inv), (short)f2bf(ot0[3]*inv) };
    bfx4 s1 = { (short)f2bf(ot1[0]*inv), (short)f2bf(ot1[1]*inv),
                (short)f2bf(ot1[2]*inv), (short)f2bf(ot1[3]*inv) };
    bfx4 s2 = { (short)f2bf(ot2[0]*inv), (short)f2bf(ot2[1]*inv),
                (short)f2bf(ot2[2]*inv), (short)f2bf(ot2[3]*inv) };
    bfx4 s3 = { (short)f2bf(ot3[0]*inv), (short)f2bf(ot3[1]*inv),
                (short)f2bf(ot3[2]*inv), (short)f2bf(ot3[3]*inv) };
    *(bfx4*)(op)      = s0;
    *(bfx4*)(op + 16) = s1;
    *(bfx4*)(op + 32) = s2;
    *(bfx4*)(op + 48) = s3;
}

// ---------------------------------------------------------------------------
extern "C" void kernel_launch(void* const* d_in, const int* in_sizes, int n_in,
                              void* d_out, int out_size, void* d_ws, size_t ws_size,
                              hipStream_t stream)
{
    const float* x       = (const float*)d_in[0];
    const float* qkv_w   = (const float*)d_in[2];
    const float* dense_w = (const float*)d_in[3];
    for (int i = 0; i < n_in; ++i) {
        if (in_sizes[i] == S_LEN * HSZ)      x       = (const float*)d_in[i];
        else if (in_sizes[i] == HSZ * QKVN)  qkv_w   = (const float*)d_in[i];
        else if (in_sizes[i] == HSZ * HSZ)   dense_w = (const float*)d_in[i];
    }
    float* out = (float*)d_out;

    // workspace (u16 elems), peak 81.6 MB (R6 proved ws_size suffices)
    const size_t E_XB  = (size_t)S_LEN * HSZ;
    const size_t E_WT  = (size_t)QKVP * HSZ;
    const size_t E_QKV = (size_t)S_LEN * QKVP;
    const size_t E_KV  = (size_t)S_LEN * HDIM;

    u16* xb_at = (u16*)d_ws;           // x bf16, later attn output
    u16* wt    = xb_at + E_XB;         // w^T (qkv, then dense)
    u16* qkvp  = wt + E_WT;
    u16* kr    = qkvp + E_QKV;
    u16* vt    = kr + E_KV;            // V^T [64][2048]

    convert_bf16<<<(int)(E_XB / 8 / 256), 256, 0, stream>>>(x, xb_at, (int)E_XB);
    conv_transpose<<<dim3(HSZ / 32, QKVP / 32), 256, 0, stream>>>(qkv_w, wt, HSZ, QKVN);
    gemm128<false><<<dim3(QKVP / 128, S_LEN / 128), 256, 0, stream>>>(
        xb_at, wt, qkvp, S_LEN, HSZ, QKVP, QKVN);
    conv_transpose<<<dim3(HSZ / 32, DNP / 32), 256, 0, stream>>>(dense_w, wt, HSZ, HSZ);
    rope_kv<<<(S_LEN * 2 * HDIM) / 256, 256, 0, stream>>>(qkvp, QKVP, kr, vt);
    attn2<<<dim3(NHEADS, 32), 256, 0, stream>>>(qkvp, QKVP, kr, vt, xb_at);
    gemm128<true><<<dim3(DNP / 128, S_LEN / 128), 256, 0, stream>>>(
        xb_at, wt, out, S_LEN, HSZ, DNP, HSZ);
}

// Round 7
// 654.449 us; speedup vs baseline: 1.1527x; 1.1527x over previous
//
#include <hip/hip_runtime.h>
#include <hip/hip_bf16.h>
#include <math.h>

#define S_LEN 2048
#define NHEADS 71
#define HDIM 64
#define HSZ (NHEADS * HDIM)        // 4544
#define QKVN ((NHEADS + 2) * HDIM) // 4672
#define QKVP 4736                  // QKVN padded to 128
#define DNP  4608                  // HSZ padded to 128

typedef unsigned short u16;
typedef __attribute__((ext_vector_type(8))) short short8;
typedef __attribute__((ext_vector_type(4))) short bfx4;   // renamed: short4 collides with HIP
typedef __attribute__((ext_vector_type(4))) float floatx4;

__device__ __forceinline__ float bf2f(u16 v) {
    unsigned u = ((unsigned)v) << 16;
    return __builtin_bit_cast(float, u);
}
__device__ __forceinline__ u16 f2bf(float f) {
    unsigned u = __builtin_bit_cast(unsigned, f);
    u += 0x7fff + ((u >> 16) & 1);   // RNE
    return (u16)(u >> 16);
}

// async global->LDS, 16B per lane (wave-uniform LDS base + lane*16)
__device__ __forceinline__ void async16(const u16* g, u16* l) {
    __builtin_amdgcn_global_load_lds(
        (const __attribute__((address_space(1))) void*)g,
        (__attribute__((address_space(3))) void*)l,
        16, 0, 0);
}

// ===========================================================================
// fp32 -> bf16 elementwise (n divisible by 8)
// ===========================================================================
__global__ __launch_bounds__(256) void convert_bf16(const float* __restrict__ src,
                                                    u16* __restrict__ dst, int n)
{
    int i = (blockIdx.x * 256 + threadIdx.x) * 8;
    if (i >= n) return;
    floatx4 a = *(const floatx4*)(src + i);
    floatx4 b = *(const floatx4*)(src + i + 4);
    u16 o[8];
#pragma unroll
    for (int j = 0; j < 4; ++j) { o[j] = f2bf(a[j]); o[4 + j] = f2bf(b[j]); }
    *(short8*)(dst + i) = *(short8*)&o[0];
}

// fp32 src[K][Ns]  ->  bf16 dst[Np][K] (transposed, rows n>=Ns zero-padded)
__global__ __launch_bounds__(256) void conv_transpose(const float* __restrict__ src,
                                                      u16* __restrict__ dst,
                                                      int K, int Ns)
{
    __shared__ float t[32][33];
    const int k0 = blockIdx.x * 32, n0 = blockIdx.y * 32;
    const int tx = threadIdx.x & 31, ty = threadIdx.x >> 5;
#pragma unroll
    for (int i = 0; i < 4; ++i) {
        int r = ty + i * 8;
        int n = n0 + tx;
        t[r][tx] = (n < Ns) ? src[(size_t)(k0 + r) * Ns + n] : 0.f;
    }
    __syncthreads();
#pragma unroll
    for (int i = 0; i < 4; ++i) {
        int rr = ty + i * 8;
        dst[(size_t)(n0 + rr) * K + k0 + tx] = f2bf(t[tx][rr]);
    }
}

// ===========================================================================
// gemm128 v4: v3 + T2 XOR-swizzle on the LDS tiles (both-sides, rule #21).
// R4 counters: FETCH halved (L2 locality worked) but dur flat, MfmaUtil 16.8%
// -> stage path is NOT critical; LDS-read is: per CU slot, ds_read traffic
// ~131kB (512cy min) doubled by 16-way conflicts (SQ_LDS_BANK_CONFLICT 3.2e7
// = ~12 extra cyc/read) vs only ~320cy of MFMA.
// Conflict source: frag reads fix the 16B slot per quad while row=l15 varies
// at 128B stride -> 16 lanes on 4 banks. Fix: LDS slot s of row r holds
// global slot s^(r&7): global_load_lds keeps a LINEAR dest, the per-lane
// GLOBAL source is pre-permuted, and reads XOR the same key. Each ds_read
// then spreads 8 lanes/slot over all 8 slots = all 32 banks = 8-phase min.
// ===========================================================================
template <bool STORE_F32>
__global__ __launch_bounds__(256) void gemm128(const u16* __restrict__ A,   // [M][K]
                                               const u16* __restrict__ Bt,  // [Np][K]
                                               void* __restrict__ Cv,
                                               int M, int K, int Np, int Nreal)
{
    __shared__ u16 As[2 * 128 * 64];
    __shared__ u16 Bs[2 * 128 * 64];

    const int tid  = threadIdx.x;
    const int w    = tid >> 6, lane = tid & 63;
    const int l15  = lane & 15, quad = lane >> 4;

    // ---- XCD-aware remap: dispatch id L -> col-major chunk per XCD ----
    int bx = blockIdx.x, by = blockIdx.y;
    {
        const int nbx = gridDim.x, nby = gridDim.y;
        const int nwg = nbx * nby;
        if ((nwg & 7) == 0) {
            const int L   = by * nbx + bx;      // dispatch-linear (x fastest)
            const int g   = L & 7;              // empirical XCD round-robin
            const int s   = L >> 3;             // slot within XCD
            const int CM  = g * (nwg >> 3) + s; // col-major block index
            bx = CM / nby;
            by = CM % nby;
        }
    }
    const int bm = by * 128, bn = bx * 128;
    const int wm = (w >> 1) * 64, wn = (w & 1) * 64;

    floatx4 acc[4][4] = {};

    const int srow = w * 32 + (lane >> 3);
    // T2: lane's linear LDS slot is (lane&7); fetch the global slot that
    // belongs there under the XOR-swizzle: gslot = (lane&7) ^ (row&7),
    // row&7 == (lane>>3)&7 for every staged row (w*32, i*8 are 0 mod 8).
    const int scol = (((lane & 7) ^ ((lane >> 3) & 7)) * 8);
    const u16* Ab = A  + (size_t)(bm + srow) * K + scol;
    const u16* Bb = Bt + (size_t)(bn + srow) * K + scol;
    const int woff = (w * 32) * 64;

    const int nkt = K >> 6;   // K/64

    // ---- prologue: stage tile 0 into buffer 0 ----
#pragma unroll
    for (int i = 0; i < 4; ++i)
        async16(Ab + (size_t)(i * 8) * K, As + woff + i * 8 * 64);
#pragma unroll
    for (int i = 0; i < 4; ++i)
        async16(Bb + (size_t)(i * 8) * K, Bs + woff + i * 8 * 64);
    __syncthreads();   // compiler drains vmcnt(0) before s_barrier -> tile 0 ready

    for (int t = 0; t < nkt; ++t) {
        const int cur = t & 1;
        const u16* Asc = As + cur * (128 * 64);
        const u16* Bsc = Bs + cur * (128 * 64);

        // ---- issue next tile's async loads into the other buffer ----
        if (t + 1 < nkt) {
            const int kb = (t + 1) << 6;
            u16* Asn = As + (cur ^ 1) * (128 * 64) + woff;
            u16* Bsn = Bs + (cur ^ 1) * (128 * 64) + woff;
#pragma unroll
            for (int i = 0; i < 4; ++i)
                async16(Ab + (size_t)(i * 8) * K + kb, Asn + i * 8 * 64);
#pragma unroll
            for (int i = 0; i < 4; ++i)
                async16(Bb + (size_t)(i * 8) * K + kb, Bsn + i * 8 * 64);
        }

        // ---- compute current tile; reads apply the same XOR key (row&7) ----
        const int rk = l15 & 7;   // row&7 for all frag rows (wm, tt*16 are 0 mod 8)
#pragma unroll
        for (int kk = 0; kk < 2; ++kk) {
            short8 af[4], bfr[4];
#pragma unroll
            for (int tt = 0; tt < 4; ++tt) {
                const int slotA = ((kk * 4 + quad) ^ rk) * 8;
                af[tt]  = *(const short8*)&Asc[(wm + tt * 16 + l15) * 64 + slotA];
                bfr[tt] = *(const short8*)&Bsc[(wn + tt * 16 + l15) * 64 + slotA];
            }
#pragma unroll
            for (int mi = 0; mi < 4; ++mi)
#pragma unroll
                for (int ni = 0; ni < 4; ++ni)
                    acc[mi][ni] = __builtin_amdgcn_mfma_f32_16x16x32_bf16(
                        af[mi], bfr[ni], acc[mi][ni], 0, 0, 0);
        }

        // barrier: waits for next tile's stage (vmcnt drain) + all ds_reads done,
        // so the buffer swap is race-free.
        __syncthreads();
    }

    if (STORE_F32) {
        float* C = (float*)Cv;
#pragma unroll
        for (int mi = 0; mi < 4; ++mi)
#pragma unroll
            for (int ni = 0; ni < 4; ++ni) {
                int col  = bn + wn + ni * 16 + l15;
                int row0 = bm + wm + mi * 16 + quad * 4;
                if (col < Nreal) {
#pragma unroll
                    for (int r = 0; r < 4; ++r)
                        C[(size_t)(row0 + r) * Nreal + col] = acc[mi][ni][r];
                }
            }
    } else {
        u16* C = (u16*)Cv;
#pragma unroll
        for (int mi = 0; mi < 4; ++mi)
#pragma unroll
            for (int ni = 0; ni < 4; ++ni) {
                int col  = bn + wn + ni * 16 + l15;
                int row0 = bm + wm + mi * 16 + quad * 4;
#pragma unroll
                for (int r = 0; r < 4; ++r)
                    C[(size_t)(row0 + r) * Np + col] = f2bf(acc[mi][ni][r]);
            }
    }
}

// ===========================================================================
// RoPE for K + V transposed to [HDIM][S_LEN]
// ===========================================================================
__global__ void rope_kv(const u16* __restrict__ qkv, int QP,
                        u16* __restrict__ Kr,   // [S][64]
                        u16* __restrict__ VT)   // [64][S]
{
    int idx = blockIdx.x * 256 + threadIdx.x;  // over S_LEN * 128
    int s = idx >> 7;
    int c = idx & 127;
    if (c < HDIM) {
        int d = c;
        float x  = bf2f(qkv[(size_t)s * QP + HSZ + d]);
        int dp   = (d < 32) ? d + 32 : d - 32;
        float rot = (d < 32) ? -bf2f(qkv[(size_t)s * QP + HSZ + dp])
                             :  bf2f(qkv[(size_t)s * QP + HSZ + dp]);
        float invf = expf(-(float)(d & 31) * 0.28782313662425572f);
        float ang  = (float)s * invf;
        float o = x * cosf(ang) + rot * sinf(ang);
        Kr[(size_t)s * HDIM + d] = f2bf(o);
    } else {
        int d = c - HDIM;
        VT[(size_t)d * S_LEN + s] = qkv[(size_t)s * QP + (NHEADS + 1) * HDIM + d];
    }
}

// ===========================================================================
// Fused causal attention v3: transposed-score formulation.
//  S^T = K·Q^T  (C rows = t, cols = q)  -> per-lane softmax state (q = lane&15)
//  O^T = V^T·P^T via 16x16x32, FULL-K: two adjacent 16-t subtiles packed into
//  k-slots 0-3 / 4-7 of one MFMA (halves PV MFMA count vs half-K trick).
// Block = (head, q-tile of 64 rows) , 4 waves x 16 q rows. 128-t chunks.
// ===========================================================================
__global__ __launch_bounds__(256) void attn2(const u16* __restrict__ qkv, int QP,
                                             const u16* __restrict__ Kr,   // [S][64]
                                             const u16* __restrict__ VT,   // [64][S]
                                             u16* __restrict__ O)          // [S][HSZ]
{
    __shared__ u16 Kt[128][72];    // [t][d]   row stride 144 B
    __shared__ u16 Vt[64][136];    // [d][t]   row stride 272 B

    const int tid  = threadIdx.x;
    const int h    = blockIdx.x;
    const int qt   = 31 - blockIdx.y;    // longest blocks dispatch first
    const int qs   = qt * 64;
    const int w    = tid >> 6;
    const int lane = tid & 63;
    const int l15  = lane & 15;
    const int quad = lane >> 4;

    // ---- Q fragments (B-operand layout: n=q=l15, k=d=quad*8+j), RoPE+scale ----
    const int q_row = qs + w * 16 + l15;
    const u16* qp = qkv + (size_t)q_row * QP + h * HDIM;
    short8 r0 = *(const short8*)(qp + quad * 8);
    short8 r1 = *(const short8*)(qp + 32 + quad * 8);
    short8 qf0, qf1;
#pragma unroll
    for (int j = 0; j < 8; ++j) {
        int d0 = quad * 8 + j;
        float invf = expf(-(float)d0 * 0.28782313662425572f);
        float ang  = (float)q_row * invf;
        float cs = cosf(ang), sn = sinf(ang);
        float x0 = bf2f((u16)r0[j]), x1 = bf2f((u16)r1[j]);
        qf0[j] = (short)f2bf((x0 * cs - x1 * sn) * 0.125f);
        qf1[j] = (short)f2bf((x1 * cs + x0 * sn) * 0.125f);
    }

    floatx4 ot0 = {0.f,0.f,0.f,0.f}, ot1 = {0.f,0.f,0.f,0.f};
    floatx4 ot2 = {0.f,0.f,0.f,0.f}, ot3 = {0.f,0.f,0.f,0.f};
    float m_p = -1e30f, l_p = 0.f;
    const int qmin_w  = qs + w * 16;
    const int nchunks = (qt + 2) >> 1;

    const int krow = tid >> 1, kcol = (tid & 1) * 32;
    const int vrow = tid >> 2, vcol = (tid & 3) * 32;

    for (int c = 0; c < nchunks; ++c) {
        const int cbase = c * 128;

        // ---- prefetch chunk to regs (overlaps prior compute), then stage ----
        const u16* kp = Kr + (size_t)(cbase + krow) * HDIM + kcol;
        short8 k0 = *(const short8*)(kp);
        short8 k1 = *(const short8*)(kp + 8);
        short8 k2 = *(const short8*)(kp + 16);
        short8 k3 = *(const short8*)(kp + 24);
        const u16* vp = VT + (size_t)vrow * S_LEN + cbase + vcol;
        short8 v0 = *(const short8*)(vp);
        short8 v1 = *(const short8*)(vp + 8);
        short8 v2 = *(const short8*)(vp + 16);
        short8 v3 = *(const short8*)(vp + 24);
        __syncthreads();
        *(short8*)&Kt[krow][kcol]      = k0;
        *(short8*)&Kt[krow][kcol + 8]  = k1;
        *(short8*)&Kt[krow][kcol + 16] = k2;
        *(short8*)&Kt[krow][kcol + 24] = k3;
        *(short8*)&Vt[vrow][vcol]      = v0;
        *(short8*)&Vt[vrow][vcol + 8]  = v1;
        *(short8*)&Vt[vrow][vcol + 16] = v2;
        *(short8*)&Vt[vrow][vcol + 24] = v3;
        __syncthreads();

        // ---- active 16-t subtiles for this wave (causal early-out) ----
        const int nsub = min(8, ((qmin_w - cbase) >> 4) + 1);

        // ---- scores S^T: rows t = cbase + s*16 + quad*4 + r, col q = l15 ----
        floatx4 sc[8];
        float tmax = -3e38f;
#pragma unroll
        for (int s = 0; s < 8; ++s) {
            if (s < nsub) {
                short8 ka = *(const short8*)&Kt[s * 16 + l15][quad * 8];
                short8 kb = *(const short8*)&Kt[s * 16 + l15][32 + quad * 8];
                floatx4 a = {0.f,0.f,0.f,0.f};
                __builtin_amdgcn_s_setprio(1);
                a = __builtin_amdgcn_mfma_f32_16x16x32_bf16(ka, qf0, a, 0, 0, 0);
                a = __builtin_amdgcn_mfma_f32_16x16x32_bf16(kb, qf1, a, 0, 0, 0);
                __builtin_amdgcn_s_setprio(0);
                if (cbase + s * 16 + 15 > qmin_w) {   // diagonal subtile: mask t>q
                    int tb = cbase + s * 16 + quad * 4;
#pragma unroll
                    for (int r = 0; r < 4; ++r)
                        if (tb + r > q_row) a[r] = -1e30f;
                }
                sc[s] = a;
                tmax = fmaxf(tmax, fmaxf(fmaxf(a[0], a[1]), fmaxf(a[2], a[3])));
            }
        }
        // reduce over t across quads (lanes sharing l15=q): 2 shuffles
        tmax = fmaxf(tmax, __shfl_xor(tmax, 16, 64));
        tmax = fmaxf(tmax, __shfl_xor(tmax, 32, 64));

        float mnew = fmaxf(m_p, tmax);
        float al   = __expf(m_p - mnew);
        m_p = mnew;
        ot0 *= al; ot1 *= al; ot2 *= al; ot3 *= al;

        float lsum = 0.f;
        // ---- PV: pair subtiles (s, s+1) into one full-K=32 MFMA group ----
#pragma unroll
        for (int s = 0; s < 8; s += 2) {
            if (s < nsub) {
                const bool two = (s + 1 < nsub);   // wave-uniform
                float p0 = __expf(sc[s][0] - mnew);
                float p1 = __expf(sc[s][1] - mnew);
                float p2 = __expf(sc[s][2] - mnew);
                float p3 = __expf(sc[s][3] - mnew);
                float p4 = 0.f, p5 = 0.f, p6 = 0.f, p7 = 0.f;
                if (two) {
                    p4 = __expf(sc[s + 1][0] - mnew);
                    p5 = __expf(sc[s + 1][1] - mnew);
                    p6 = __expf(sc[s + 1][2] - mnew);
                    p7 = __expf(sc[s + 1][3] - mnew);
                }
                lsum += ((p0 + p1) + (p2 + p3)) + ((p4 + p5) + (p6 + p7));
                short8 pb = { (short)f2bf(p0), (short)f2bf(p1),
                              (short)f2bf(p2), (short)f2bf(p3),
                              (short)f2bf(p4), (short)f2bf(p5),
                              (short)f2bf(p6), (short)f2bf(p7) };
                const int vc0 = s * 16 + quad * 4;
                const int vc1 = vc0 + 16;
                bfx4 z = {0, 0, 0, 0};
                bfx4 lo0 = *(const bfx4*)&Vt[l15][vc0];
                bfx4 lo1 = *(const bfx4*)&Vt[16 + l15][vc0];
                bfx4 lo2 = *(const bfx4*)&Vt[32 + l15][vc0];
                bfx4 lo3 = *(const bfx4*)&Vt[48 + l15][vc0];
                bfx4 hi0 = z, hi1 = z, hi2 = z, hi3 = z;
                if (two) {
                    hi0 = *(const bfx4*)&Vt[l15][vc1];
                    hi1 = *(const bfx4*)&Vt[16 + l15][vc1];
                    hi2 = *(const bfx4*)&Vt[32 + l15][vc1];
                    hi3 = *(const bfx4*)&Vt[48 + l15][vc1];
                }
                short8 a0 = { lo0[0], lo0[1], lo0[2], lo0[3], hi0[0], hi0[1], hi0[2], hi0[3] };
                short8 a1 = { lo1[0], lo1[1], lo1[2], lo1[3], hi1[0], hi1[1], hi1[2], hi1[3] };
                short8 a2 = { lo2[0], lo2[1], lo2[2], lo2[3], hi2[0], hi2[1], hi2[2], hi2[3] };
                short8 a3 = { lo3[0], lo3[1], lo3[2], lo3[3], hi3[0], hi3[1], hi3[2], hi3[3] };
                __builtin_amdgcn_s_setprio(1);
                ot0 = __builtin_amdgcn_mfma_f32_16x16x32_bf16(a0, pb, ot0, 0, 0, 0);
                ot1 = __builtin_amdgcn_mfma_f32_16x16x32_bf16(a1, pb, ot1, 0, 0, 0);
                ot2 = __builtin_amdgcn_mfma_f32_16x16x32_bf16(a2, pb, ot2, 0, 0, 0);
                ot3 = __builtin_amdgcn_mfma_f32_16x16x32_bf16(a3, pb, ot3, 0, 0, 0);
                __builtin_amdgcn_s_setprio(0);
            }
        }
        lsum += __shfl_xor(lsum, 16, 64);
        lsum += __shfl_xor(lsum, 32, 64);
        l_p = l_p * al + lsum;
    }

    // ---- epilogue: O^T rows d = dt*16 + quad*4 + r, col q = l15 ----
    float inv = 1.0f / l_p;
    u16* op = O + (size_t)q_row * HSZ + h * HDIM + quad * 4;
    bfx4 s0 = { (short)f2bf(ot0[0]*inv), (short)f2bf(ot0[1]*inv),
                (short)f2bf(ot0[2]*inv), (short)f2bf(ot0[3]*inv) };
    bfx4 s1 = { (short)f2bf(ot1[0]*inv), (short)f2bf(ot1[1]*inv),
                (short)f2bf(ot1[2]*inv), (short)f2bf(ot1[3]*inv) };
    bfx4 s2 = { (short)f2bf(ot2[0]*inv), (short)f2bf(ot2[1]*inv),
                (short)f2bf(ot2[2]*inv), (short)f2bf(ot2[3]*inv) };
    bfx4 s3 = { (short)f2bf(ot3[0]*inv), (short)f2bf(ot3[1]*inv),
                (short)f2bf(ot3[2]*inv), (short)f2bf(ot3[3]*inv) };
    *(bfx4*)(op)      = s0;
    *(bfx4*)(op + 16) = s1;
    *(bfx4*)(op + 32) = s2;
    *(bfx4*)(op + 48) = s3;
}

// ---------------------------------------------------------------------------
extern "C" void kernel_launch(void* const* d_in, const int* in_sizes, int n_in,
                              void* d_out, int out_size, void* d_ws, size_t ws_size,
                              hipStream_t stream)
{
    const float* x       = (const float*)d_in[0];
    const float* qkv_w   = (const float*)d_in[2];
    const float* dense_w = (const float*)d_in[3];
    for (int i = 0; i < n_in; ++i) {
        if (in_sizes[i] == S_LEN * HSZ)      x       = (const float*)d_in[i];
        else if (in_sizes[i] == HSZ * QKVN)  qkv_w   = (const float*)d_in[i];
        else if (in_sizes[i] == HSZ * HSZ)   dense_w = (const float*)d_in[i];
    }
    float* out = (float*)d_out;

    // workspace (u16 elems), peak 81.6 MB (R6 proved ws_size suffices)
    const size_t E_XB  = (size_t)S_LEN * HSZ;
    const size_t E_WT  = (size_t)QKVP * HSZ;
    const size_t E_QKV = (size_t)S_LEN * QKVP;
    const size_t E_KV  = (size_t)S_LEN * HDIM;

    u16* xb_at = (u16*)d_ws;           // x bf16, later attn output
    u16* wt    = xb_at + E_XB;         // w^T (qkv, then dense)
    u16* qkvp  = wt + E_WT;
    u16* kr    = qkvp + E_QKV;
    u16* vt    = kr + E_KV;            // V^T [64][2048]

    convert_bf16<<<(int)(E_XB / 8 / 256), 256, 0, stream>>>(x, xb_at, (int)E_XB);
    conv_transpose<<<dim3(HSZ / 32, QKVP / 32), 256, 0, stream>>>(qkv_w, wt, HSZ, QKVN);
    gemm128<false><<<dim3(QKVP / 128, S_LEN / 128), 256, 0, stream>>>(
        xb_at, wt, qkvp, S_LEN, HSZ, QKVP, QKVN);
    conv_transpose<<<dim3(HSZ / 32, DNP / 32), 256, 0, stream>>>(dense_w, wt, HSZ, HSZ);
    rope_kv<<<(S_LEN * 2 * HDIM) / 256, 256, 0, stream>>>(qkvp, QKVP, kr, vt);
    attn2<<<dim3(NHEADS, 32), 256, 0, stream>>>(qkvp, QKVP, kr, vt, xb_at);
    gemm128<true><<<dim3(DNP / 128, S_LEN / 128), 256, 0, stream>>>(
        xb_at, wt, out, S_LEN, HSZ, DNP, HSZ);
}